// Round 8
// baseline (775.511 us; speedup 1.0000x reference)
//
#include <hip/hip_runtime.h>
#include <hip/hip_cooperative_groups.h>
#include <math.h>

namespace cg = cooperative_groups;

// N nodes (50000), E edges (600000), D=128.
// Q = x@Wq.T; K = x@Wk.T; V = x@Wv.T  (node-level)
// per edge e=(s->d): c = sigmoid(dot(Q[d],K[s])/sqrt(128)); agg[d] += c*V[s]
// out = LN(x + agg@Wo.T + bo) * gamma + beta
//
// R2..R8: counting-sort + per-node agg; split-bf16 MFMA GEMMs; K/V bf16
//     interleaved; node_agg sublane layout + superbatch + 1-deep pipeline;
//     Q bf16 pre-scaled. qkv (LDS, BM=64) = 46 us, node_agg ~45 us.
// R9: qkv grid x3 mat-split REGRESSED (staging tripled: 61.7 us).
// R10: qkv no-LDS reg-A REGRESSED HARD (107.8): B-stream x4 at 3 waves/SIMD.
// R11/R13: qkv QBM=32 REGRESSED (56 us): per-block B-traffic constant ->
//     doubling grid doubled B-reads. BM=64 is the tile optimum. Reverted.
// R14: totals never track per-kernel wins (R2: 268 total vs ~150 kernel sum;
//     removing 1 launch = -12.6 us). Launch bubbles are first-class cost.
//     -> ONE cooperative kernel (grid.sync phases) replaces the 5-kernel
//        preprocessing chain: zero+split -> hist -> scan -> add -> scatter.
//        8 launches -> 4. Fallback to 5-kernel path if coop launch fails.

#define BM 64      /* qkv + out_ln tile */
#define QSCALE -0.08838834764831845f   /* -1/sqrt(128), folded into Q */

typedef __attribute__((ext_vector_type(8))) short bfrag;   // 8 bf16 = 4 VGPRs
typedef __attribute__((ext_vector_type(4))) float f32x4;

__device__ __forceinline__ short f2bf(float f) {
    union { float f; unsigned u; } v; v.f = f;
    unsigned r = v.u + 0x7FFFu + ((v.u >> 16) & 1u);   // round-to-nearest-even
    return (short)(r >> 16);
}
__device__ __forceinline__ float bf2f(short h) {
    union { unsigned u; float f; } v;
    v.u = ((unsigned)(unsigned short)h) << 16;
    return v.f;
}
// dword holds (K at low ushort, V at high ushort)
__device__ __forceinline__ float klo(unsigned w) {
    union { unsigned u; float f; } v; v.u = w << 16; return v.f;
}
__device__ __forceinline__ float vhi(unsigned w) {
    union { unsigned u; float f; } v; v.u = w & 0xffff0000u; return v.f;
}

#define SWZ(x, pat) __int_as_float(__builtin_amdgcn_ds_swizzle(__float_as_int(x), pat))

// ======== R14: cooperative preprocessing (1 launch replaces 5) ========
// phases: (0) zero hist + weight split  (1) histogram  (2) chunk scan
// (3) blockSums scan  (4) prefix add -> offs/starts  (5) scatter
// Assumes N <= 65536 (nScan <= 64 fits one wave in phase 3).
__global__ __launch_bounds__(256) void preprocess_coop(
    const int* __restrict__ ei,
    const float* __restrict__ Wq, const float* __restrict__ Wk,
    const float* __restrict__ Wv, const float* __restrict__ Wo,
    short* __restrict__ whi, short* __restrict__ wlo,
    int* __restrict__ hist, int* __restrict__ offs, int* __restrict__ starts,
    int* __restrict__ blockSums, int* __restrict__ ssrc,
    int N, int E, int nScan)
{
    cg::grid_group grid = cg::this_grid();
    __shared__ int sdata[256];
    const int t = threadIdx.x;
    const int gtid = blockIdx.x * 256 + t;
    const int gsize = gridDim.x * 256;

    // phase 0: zero hist + split weights fp32 -> bf16 hi/lo
    for (int i = gtid; i < N; i += gsize) hist[i] = 0;
    for (int g = gtid; g < 65536; g += gsize) {
        const float* Ws[4] = {Wq, Wk, Wv, Wo};
        float f = Ws[g >> 14][g & 16383];
        short h = f2bf(f);
        whi[g] = h; wlo[g] = f2bf(f - bf2f(h));
    }
    grid.sync();

    // phase 1: histogram of dst
    for (int e = gtid; e < E; e += gsize) atomicAdd(&hist[ei[E + e]], 1);
    grid.sync();

    // phase 2: per-chunk exclusive scan (1024 elems/chunk)
    for (int chunk = blockIdx.x; chunk < nScan; chunk += gridDim.x) {
        int base = chunk * 1024 + t * 4;
        int v[4]; int tot = 0;
        #pragma unroll
        for (int j = 0; j < 4; ++j) {
            int idx = base + j;
            v[j] = (idx < N) ? hist[idx] : 0;
            tot += v[j];
        }
        sdata[t] = tot;
        __syncthreads();
        for (int off = 1; off < 256; off <<= 1) {
            int xv = (t >= off) ? sdata[t - off] : 0;
            __syncthreads();
            sdata[t] += xv;
            __syncthreads();
        }
        int run = sdata[t] - tot;
        #pragma unroll
        for (int j = 0; j < 4; ++j) {
            int idx = base + j;
            if (idx < N) offs[idx] = run;
            run += v[j];
        }
        if (t == 255) blockSums[chunk] = sdata[t];
        __syncthreads();
    }
    grid.sync();

    // phase 3: exclusive scan of blockSums (nScan <= 64) on one wave
    if (blockIdx.x == 0 && t < 64) {
        int orig = (t < nScan) ? blockSums[t] : 0;
        int v = orig;
        #pragma unroll
        for (int off = 1; off < 64; off <<= 1) {
            int u = __shfl_up(v, off);
            if (t >= off) v += u;
        }
        if (t < nScan) blockSums[t] = v - orig;   // exclusive prefix
    }
    grid.sync();

    // phase 4: add chunk prefix; write offs (consumable) + starts (kept)
    for (int i = gtid; i < N; i += gsize) {
        int vv = offs[i] + blockSums[i >> 10];
        offs[i] = vv;
        starts[i] = vv;
    }
    grid.sync();

    // phase 5: scatter edges by dst
    for (int e = gtid; e < E; e += gsize) {
        int d = ei[E + e];
        int pos = atomicAdd(&offs[d], 1);
        ssrc[pos] = ei[e];
    }
}

// ---------- fallback (non-coop) path: original 5 kernels ----------
__global__ __launch_bounds__(256) void zero_prep(
    const float* __restrict__ Wq, const float* __restrict__ Wk,
    const float* __restrict__ Wv, const float* __restrict__ Wo,
    short* __restrict__ whi, short* __restrict__ wlo,
    int* __restrict__ hist, int N)
{
    int g = blockIdx.x * 256 + threadIdx.x;
    if (g < N) hist[g] = 0;
    if (g < 65536) {
        const float* Ws[4] = {Wq, Wk, Wv, Wo};
        float f = Ws[g >> 14][g & 16383];
        short h = f2bf(f);
        short l = f2bf(f - bf2f(h));
        whi[g] = h; wlo[g] = l;
    }
}

__global__ __launch_bounds__(256) void hist_kernel(
    const int* __restrict__ ei, int* __restrict__ hist, int E)
{
    int e = blockIdx.x * blockDim.x + threadIdx.x;
    if (e < E) atomicAdd(&hist[ei[E + e]], 1);
}

#define SCAN_TPB 256
#define SCAN_EPT 4

__global__ __launch_bounds__(SCAN_TPB) void scan_partial(
    const int* __restrict__ hist, int* __restrict__ offs,
    int* __restrict__ blockSums, int N)
{
    __shared__ int sdata[SCAN_TPB];
    int b = blockIdx.x;
    int t = threadIdx.x;
    int base = b * SCAN_TPB * SCAN_EPT + t * SCAN_EPT;
    int v[SCAN_EPT];
    int tot = 0;
    #pragma unroll
    for (int j = 0; j < SCAN_EPT; ++j) {
        int idx = base + j;
        v[j] = (idx < N) ? hist[idx] : 0;
        tot += v[j];
    }
    sdata[t] = tot;
    __syncthreads();
    for (int off = 1; off < SCAN_TPB; off <<= 1) {
        int xv = (t >= off) ? sdata[t - off] : 0;
        __syncthreads();
        sdata[t] += xv;
        __syncthreads();
    }
    int run = sdata[t] - tot;
    #pragma unroll
    for (int j = 0; j < SCAN_EPT; ++j) {
        int idx = base + j;
        if (idx < N) offs[idx] = run;
        run += v[j];
    }
    if (t == SCAN_TPB - 1) blockSums[b] = sdata[t];
}

__global__ __launch_bounds__(256) void scan_add(
    int* __restrict__ offs, int* __restrict__ starts,
    const int* __restrict__ blockSums, int N, int nb)
{
    __shared__ int bs[64];
    int t = threadIdx.x;
    if (t < 64) {
        int v = (t < nb) ? blockSums[t] : 0;
        #pragma unroll
        for (int off = 1; off < 64; off <<= 1) {
            int u = __shfl_up(v, off);
            if (t >= off) v += u;
        }
        bs[t] = v;
    }
    __syncthreads();
    int idx = blockIdx.x * blockDim.x + threadIdx.x;
    if (idx < N) {
        int blk = idx >> 10;
        int pref = (blk == 0) ? 0 : bs[blk - 1];
        int vv = offs[idx] + pref;
        offs[idx] = vv;
        starts[idx] = vv;
    }
}

__global__ __launch_bounds__(256) void scatter_kernel(
    const int* __restrict__ ei, int* __restrict__ offs,
    int* __restrict__ ssrc, int E)
{
    int e = blockIdx.x * blockDim.x + threadIdx.x;
    if (e < E) {
        int d = ei[E + e];
        int pos = atomicAdd(&offs[d], 1);
        ssrc[pos] = ei[e];
    }
}

// ---------------- fused QKV projection via split-bf16 MFMA ----------------
// R8 structure, BM=64 (proven 46 us). Q written bf16 pre-scaled by
// -1/sqrt(128); K,V element-interleaved bf16:
// KV16[node*256 + 2*i] = K[node][i], KV16[node*256 + 2*i + 1] = V[node][i]
__global__ __launch_bounds__(256) void qkv_mfma(
    const float* __restrict__ x,
    const short* __restrict__ whi, const short* __restrict__ wlo,
    unsigned short* __restrict__ Q16, unsigned short* __restrict__ KV16, int N)
{
    __shared__ short xs_hi[64][136];   // +8 pad: row 272 B -> 2-way LDS (free)
    __shared__ short xs_lo[64][136];

    const int tid = threadIdx.x;
    const int row0 = blockIdx.x * BM;

    #pragma unroll
    for (int i = 0; i < 8; ++i) {      // 64 rows x 32 float4 = 2048 = 256*8
        int idx = tid + 256 * i;
        int r = idx >> 5;
        int c4 = idx & 31;
        int gr = row0 + r;
        float4 val = make_float4(0.f, 0.f, 0.f, 0.f);
        if (gr < N) val = ((const float4*)(x + (size_t)gr * 128))[c4];
        short4 h, l;
        h.x = f2bf(val.x); l.x = f2bf(val.x - bf2f(h.x));
        h.y = f2bf(val.y); l.y = f2bf(val.y - bf2f(h.y));
        h.z = f2bf(val.z); l.z = f2bf(val.z - bf2f(h.z));
        h.w = f2bf(val.w); l.w = f2bf(val.w - bf2f(h.w));
        *((short4*)&xs_hi[r][c4 * 4]) = h;
        *((short4*)&xs_lo[r][c4 * 4]) = l;
    }
    __syncthreads();

    const int wid  = tid >> 6;
    const int lane = tid & 63;
    const int n16  = lane & 15;
    const int quad = lane >> 4;

    #pragma unroll 1
    for (int mat = 0; mat < 3; ++mat) {
        const short* __restrict__ WH = whi + mat * 16384;
        const short* __restrict__ WL = wlo + mat * 16384;
        const f32x4 zero = {0.f, 0.f, 0.f, 0.f};
        f32x4 acc[4][2];
        #pragma unroll
        for (int t = 0; t < 4; ++t) { acc[t][0] = zero; acc[t][1] = zero; }

        #pragma unroll
        for (int kc = 0; kc < 4; ++kc) {
            int k0 = kc * 32 + quad * 8;
            bfrag ah[4], al[4], bh[2], bl[2];
            #pragma unroll
            for (int t = 0; t < 4; ++t) {
                ah[t] = *((const bfrag*)&xs_hi[t * 16 + n16][k0]);
                al[t] = *((const bfrag*)&xs_lo[t * 16 + n16][k0]);
            }
            #pragma unroll
            for (int c = 0; c < 2; ++c) {
                int wr = (wid * 2 + c) * 16 + n16;
                bh[c] = *((const bfrag*)(WH + wr * 128 + k0));
                bl[c] = *((const bfrag*)(WL + wr * 128 + k0));
            }
            #pragma unroll
            for (int t = 0; t < 4; ++t)
                #pragma unroll
                for (int c = 0; c < 2; ++c) {
                    acc[t][c] = __builtin_amdgcn_mfma_f32_16x16x32_bf16(ah[t], bh[c], acc[t][c], 0, 0, 0);
                    acc[t][c] = __builtin_amdgcn_mfma_f32_16x16x32_bf16(al[t], bh[c], acc[t][c], 0, 0, 0);
                    acc[t][c] = __builtin_amdgcn_mfma_f32_16x16x32_bf16(ah[t], bl[c], acc[t][c], 0, 0, 0);
                }
        }
        #pragma unroll
        for (int t = 0; t < 4; ++t)
            #pragma unroll
            for (int r = 0; r < 4; ++r) {
                int grow = row0 + t * 16 + quad * 4 + r;
                if (grow < N) {
                    int c0 = (wid * 2 + 0) * 16 + n16;
                    int c1 = (wid * 2 + 1) * 16 + n16;
                    if (mat == 0) {
                        Q16[(size_t)grow * 128 + c0] = (unsigned short)f2bf(acc[t][0][r] * QSCALE);
                        Q16[(size_t)grow * 128 + c1] = (unsigned short)f2bf(acc[t][1][r] * QSCALE);
                    } else {
                        size_t base = (size_t)grow * 256 + (mat - 1);  // K at +0, V at +1
                        KV16[base + 2 * c0] = (unsigned short)f2bf(acc[t][0][r]);
                        KV16[base + 2 * c1] = (unsigned short)f2bf(acc[t][1][r]);
                    }
                }
            }
    }
}

// ---------------- per-node attention aggregation (no atomics) ----------------
// One wave per dst node; 4 edge slots (lane>>4) x 16 sublanes (lane&15) x 8
// elements; one 4-step swizzle allreduce serves 4 edges. Superbatch index
// preload: lane l holds ssrc[base+l], per-batch indices via __shfl; KV
// prefetch for batch b+1 issued before computing batch b.
__global__ __launch_bounds__(256) void node_agg(
    const int* __restrict__ ssrc,
    const int* __restrict__ starts,
    const int* __restrict__ endoffs,
    const unsigned short* __restrict__ Q16,
    const unsigned short* __restrict__ KV16,
    float* __restrict__ agg, int N)
{
    int node = blockIdx.x * 4 + (threadIdx.x >> 6);
    if (node >= N) return;
    int lane = threadIdx.x & 63;
    int eg   = lane >> 4;        // edge slot 0..3
    int sl   = lane & 15;        // element group: elements sl*8 .. sl*8+7
    int start = starts[node];
    int end   = endoffs[node];

    if (start >= end) {          // degree-0 node: zero output, avoid ssrc[-1]
        if (eg == 0) {
            *((float4*)(agg + (size_t)node * 128 + sl * 8))     = make_float4(0.f, 0.f, 0.f, 0.f);
            *((float4*)(agg + (size_t)node * 128 + sl * 8 + 4)) = make_float4(0.f, 0.f, 0.f, 0.f);
        }
        return;
    }

    // q: one 16B bf16x8 load, unpacked once
    bfrag qv = *((const bfrag*)(Q16 + (size_t)node * 128 + sl * 8));
    float q0x = bf2f(qv[0]), q0y = bf2f(qv[1]), q0z = bf2f(qv[2]), q0w = bf2f(qv[3]);
    float q1x = bf2f(qv[4]), q1y = bf2f(qv[5]), q1z = bf2f(qv[6]), q1w = bf2f(qv[7]);

    float a0 = 0.f, a1 = 0.f, a2 = 0.f, a3 = 0.f;
    float a4 = 0.f, a5 = 0.f, a6 = 0.f, a7 = 0.f;

    const unsigned short* kvbase = KV16 + sl * 16;   // + s*256 per edge

    for (int base = start; base < end; base += 64) {   // superbatch (deg<=64: once)
        int li = base + lane;
        li = (li < end) ? li : (end - 1);
        int sidx = ssrc[li];                            // 64 indices in one load
        int nb   = end - base;
        if (nb > 64) nb = 64;
        int nbat = (nb + 7) >> 3;                       // 1..8 batches of 8 edges

        // batch 0 loads
        int s0 = __shfl(sidx, eg);
        int s1 = __shfl(sidx, 4 + eg);
        const unsigned short* kp0 = kvbase + ((size_t)s0 << 8);
        const unsigned short* kp1 = kvbase + ((size_t)s1 << 8);
        uint4 wa0 = *((const uint4*)kp0);
        uint4 wa1 = *((const uint4*)(kp0 + 8));
        uint4 wb0 = *((const uint4*)kp1);
        uint4 wb1 = *((const uint4*)(kp1 + 8));

        for (int b = 0;;) {
            bool more = (b + 1) < nbat;                 // wave-uniform
            uint4 na0, na1, nb0, nb1;
            if (more) {                                  // prefetch batch b+1
                int t0 = __shfl(sidx, 8 * (b + 1) + eg);
                int t1 = __shfl(sidx, 8 * (b + 1) + 4 + eg);
                const unsigned short* np0 = kvbase + ((size_t)t0 << 8);
                const unsigned short* np1 = kvbase + ((size_t)t1 << 8);
                na0 = *((const uint4*)np0);
                na1 = *((const uint4*)(np0 + 8));
                nb0 = *((const uint4*)np1);
                nb1 = *((const uint4*)(np1 + 8));
            }

            int ok0 = ((base + 8 * b + eg) < end);
            int ok1 = ((base + 8 * b + 4 + eg) < end);

            // dot products (K in low ushort of each dword)
            float p0, p1;
            p0 = q0x * klo(wa0.x);
            p0 = fmaf(q0y, klo(wa0.y), p0);
            p0 = fmaf(q0z, klo(wa0.z), p0);
            p0 = fmaf(q0w, klo(wa0.w), p0);
            p0 = fmaf(q1x, klo(wa1.x), p0);
            p0 = fmaf(q1y, klo(wa1.y), p0);
            p0 = fmaf(q1z, klo(wa1.z), p0);
            p0 = fmaf(q1w, klo(wa1.w), p0);
            p1 = q0x * klo(wb0.x);
            p1 = fmaf(q0y, klo(wb0.y), p1);
            p1 = fmaf(q0z, klo(wb0.z), p1);
            p1 = fmaf(q0w, klo(wb0.w), p1);
            p1 = fmaf(q1x, klo(wb1.x), p1);
            p1 = fmaf(q1y, klo(wb1.y), p1);
            p1 = fmaf(q1z, klo(wb1.z), p1);
            p1 = fmaf(q1w, klo(wb1.w), p1);

            // 4-step allreduce within each 16-lane group (4 edges at once)
            p0 += SWZ(p0, 0x041F); p1 += SWZ(p1, 0x041F);
            p0 += SWZ(p0, 0x081F); p1 += SWZ(p1, 0x081F);
            p0 += SWZ(p0, 0x101F); p1 += SWZ(p1, 0x101F);
            p0 += SWZ(p0, 0x201F); p1 += SWZ(p1, 0x201F);

            // sigmoid(q.k/sqrt(D)): Q pre-scaled negative -> c = 1/(1+exp(p))
            float c0 = __builtin_amdgcn_rcpf(1.f + __expf(p0));
            float c1 = __builtin_amdgcn_rcpf(1.f + __expf(p1));
            if (!ok0) c0 = 0.f;
            if (!ok1) c1 = 0.f;

            // accumulate c*V (V in high ushort of each dword)
            a0 = fmaf(c0, vhi(wa0.x), a0); a0 = fmaf(c1, vhi(wb0.x), a0);
            a1 = fmaf(c0, vhi(wa0.y), a1); a1 = fmaf(c1, vhi(wb0.y), a1);
            a2 = fmaf(c0, vhi(wa0.z), a2); a2 = fmaf(c1, vhi(wb0.z), a2);
            a3 = fmaf(c0, vhi(wa0.w), a3); a3 = fmaf(c1, vhi(wb0.w), a3);
            a4 = fmaf(c0, vhi(wa1.x), a4); a4 = fmaf(c1, vhi(wb1.x), a4);
            a5 = fmaf(c0, vhi(wa1.y), a5); a5 = fmaf(c1, vhi(wb1.y), a5);
            a6 = fmaf(c0, vhi(wa1.z), a6); a6 = fmaf(c1, vhi(wb1.z), a6);
            a7 = fmaf(c0, vhi(wa1.w), a7); a7 = fmaf(c1, vhi(wb1.w), a7);

            if (!more) break;
            wa0 = na0; wa1 = na1; wb0 = nb0; wb1 = nb1;
            ++b;
        }
    }

    // combine the 4 edge-slot groups: xor16 (swizzle) + xor32 (shfl)
    a0 += SWZ(a0, 0x401F); a1 += SWZ(a1, 0x401F);
    a2 += SWZ(a2, 0x401F); a3 += SWZ(a3, 0x401F);
    a4 += SWZ(a4, 0x401F); a5 += SWZ(a5, 0x401F);
    a6 += SWZ(a6, 0x401F); a7 += SWZ(a7, 0x401F);
    a0 += __shfl_xor(a0, 32); a1 += __shfl_xor(a1, 32);
    a2 += __shfl_xor(a2, 32); a3 += __shfl_xor(a3, 32);
    a4 += __shfl_xor(a4, 32); a5 += __shfl_xor(a5, 32);
    a6 += __shfl_xor(a6, 32); a7 += __shfl_xor(a7, 32);

    if (eg == 0) {
        *((float4*)(agg + (size_t)node * 128 + sl * 8))     = make_float4(a0, a1, a2, a3);
        *((float4*)(agg + (size_t)node * 128 + sl * 8 + 4)) = make_float4(a4, a5, a6, a7);
    }
}

// ------- output GEMM (split-bf16 MFMA) + bias + residual + LayerNorm -------
__global__ __launch_bounds__(256) void out_ln_mfma(
    const float* __restrict__ agg,
    const short* __restrict__ whi, const short* __restrict__ wlo,  // Wo = mat 3
    const float* __restrict__ bo, const float* __restrict__ x,
    const float* __restrict__ gamma, const float* __restrict__ beta,
    float* __restrict__ out, int N)
{
    __shared__ __align__(16) char smem[64 * 136 * 2 * 2];   // 69632 B
    short (*xs_hi)[136] = (short(*)[136])smem;
    short (*xs_lo)[136] = (short(*)[136])(smem + 64 * 136 * 2);
    float (*hs)[132]    = (float(*)[132])smem;               // reused post-GEMM

    const int tid = threadIdx.x;
    const int row0 = blockIdx.x * BM;

    #pragma unroll
    for (int i = 0; i < 8; ++i) {
        int idx = tid + 256 * i;
        int r = idx >> 5;
        int c4 = idx & 31;
        int gr = row0 + r;
        float4 val = make_float4(0.f, 0.f, 0.f, 0.f);
        if (gr < N) val = ((const float4*)(agg + (size_t)gr * 128))[c4];
        short4 h, l;
        h.x = f2bf(val.x); l.x = f2bf(val.x - bf2f(h.x));
        h.y = f2bf(val.y); l.y = f2bf(val.y - bf2f(h.y));
        h.z = f2bf(val.z); l.z = f2bf(val.z - bf2f(h.z));
        h.w = f2bf(val.w); l.w = f2bf(val.w - bf2f(h.w));
        *((short4*)&xs_hi[r][c4 * 4]) = h;
        *((short4*)&xs_lo[r][c4 * 4]) = l;
    }
    __syncthreads();

    const int wid  = tid >> 6;
    const int lane = tid & 63;
    const int n16  = lane & 15;
    const int quad = lane >> 4;
    const short* __restrict__ WH = whi + 3 * 16384;
    const short* __restrict__ WL = wlo + 3 * 16384;

    const f32x4 zero = {0.f, 0.f, 0.f, 0.f};
    f32x4 acc[4][2];
    #pragma unroll
    for (int t = 0; t < 4; ++t) { acc[t][0] = zero; acc[t][1] = zero; }

    #pragma unroll
    for (int kc = 0; kc < 4; ++kc) {
        int k0 = kc * 32 + quad * 8;
        bfrag ah[4], al[4], bh[2], bl[2];
        #pragma unroll
        for (int t = 0; t < 4; ++t) {
            ah[t] = *((const bfrag*)&xs_hi[t * 16 + n16][k0]);
            al[t] = *((const bfrag*)&xs_lo[t * 16 + n16][k0]);
        }
        #pragma unroll
        for (int c = 0; c < 2; ++c) {
            int wr = (wid * 2 + c) * 16 + n16;
            bh[c] = *((const bfrag*)(WH + wr * 128 + k0));
            bl[c] = *((const bfrag*)(WL + wr * 128 + k0));
        }
        #pragma unroll
        for (int t = 0; t < 4; ++t)
            #pragma unroll
            for (int c = 0; c < 2; ++c) {
                acc[t][c] = __builtin_amdgcn_mfma_f32_16x16x32_bf16(ah[t], bh[c], acc[t][c], 0, 0, 0);
                acc[t][c] = __builtin_amdgcn_mfma_f32_16x16x32_bf16(al[t], bh[c], acc[t][c], 0, 0, 0);
                acc[t][c] = __builtin_amdgcn_mfma_f32_16x16x32_bf16(ah[t], bl[c], acc[t][c], 0, 0, 0);
            }
    }
    __syncthreads();   // all xs reads done before hs overwrite

    #pragma unroll
    for (int t = 0; t < 4; ++t)
        #pragma unroll
        for (int r = 0; r < 4; ++r) {
            hs[t * 16 + quad * 4 + r][(wid * 2 + 0) * 16 + n16] = acc[t][0][r];
            hs[t * 16 + quad * 4 + r][(wid * 2 + 1) * 16 + n16] = acc[t][1][r];
        }
    __syncthreads();

    {
        int r = tid >> 2;
        int qd = tid & 3;
        int gr = row0 + r;
        float sum = 0.f, sq = 0.f;
        #pragma unroll
        for (int c = 0; c < 32; c += 4) {
            float4 g4 = *((float4*)&hs[r][qd * 32 + c]);
            float4 b4 = *((const float4*)(bo + qd * 32 + c));
            float4 x4 = make_float4(0.f, 0.f, 0.f, 0.f);
            if (gr < N) x4 = *((const float4*)(x + (size_t)gr * 128 + qd * 32 + c));
            float4 h = make_float4(g4.x + b4.x + x4.x, g4.y + b4.y + x4.y,
                                   g4.z + b4.z + x4.z, g4.w + b4.w + x4.w);
            *((float4*)&hs[r][qd * 32 + c]) = h;
            sum += h.x + h.y + h.z + h.w;
            sq += h.x * h.x + h.y * h.y + h.z * h.z + h.w * h.w;
        }
        sum += __shfl_xor(sum, 1); sum += __shfl_xor(sum, 2);
        sq  += __shfl_xor(sq, 1);  sq  += __shfl_xor(sq, 2);
        float mu = sum * (1.f / 128.f);
        float var = sq * (1.f / 128.f) - mu * mu;
        float rs = rsqrtf(var + 1e-5f);
        if (gr < N) {
            #pragma unroll
            for (int c = 0; c < 32; c += 4) {
                float4 h = *((float4*)&hs[r][qd * 32 + c]);
                float4 g = *((const float4*)(gamma + qd * 32 + c));
                float4 b = *((const float4*)(beta + qd * 32 + c));
                float4 o = make_float4((h.x - mu) * rs * g.x + b.x,
                                       (h.y - mu) * rs * g.y + b.y,
                                       (h.z - mu) * rs * g.z + b.z,
                                       (h.w - mu) * rs * g.w + b.w);
                *((float4*)(out + (size_t)gr * 128 + qd * 32 + c)) = o;
            }
        }
    }
}

extern "C" void kernel_launch(void* const* d_in, const int* in_sizes, int n_in,
                              void* d_out, int out_size, void* d_ws, size_t ws_size,
                              hipStream_t stream) {
    const float* x     = (const float*)d_in[0];
    const int*   ei    = (const int*)d_in[1];
    const float* Wq    = (const float*)d_in[2];
    const float* Wk    = (const float*)d_in[3];
    const float* Wv    = (const float*)d_in[4];
    const float* Wo    = (const float*)d_in[5];
    const float* bo    = (const float*)d_in[6];
    const float* gamma = (const float*)d_in[7];
    const float* beta  = (const float*)d_in[8];
    const int N = in_sizes[0] / 128;
    const int E = in_sizes[1] / 2;
    const size_t ND = (size_t)N * 128;

    // workspace: Q16 bf16 12.8MB + KV16 interleaved bf16 25.6MB + agg 25.6MB
    //            + hist/offs/starts + blockSums + ssrc + whi/wlo
    unsigned short* Q16  = (unsigned short*)d_ws;
    unsigned short* KV16 = Q16 + ND;                     // 2*ND ushorts
    float* agg = (float*)(KV16 + 2 * ND);
    int* hist      = (int*)(agg + ND);
    int* offs      = hist + N;
    int* starts    = offs + N;
    int* blockSums = starts + N;       // 256 ints
    int* ssrc      = blockSums + 256;  // E ints
    short* whi     = (short*)(ssrc + E);        // 4*16384 shorts
    short* wlo     = whi + 4 * 16384;

    const int nScan = (N + 1023) / 1024;   // <= 64 for N <= 65536

    // ---- preprocessing: ONE cooperative launch (fallback: 5 kernels) ----
    {
        const int*   eip = ei;
        const float *wqp = Wq, *wkp = Wk, *wvp = Wv, *wop = Wo;
        short *whip = whi, *wlop = wlo;
        int *histp = hist, *offsp = offs, *startsp = starts,
            *bsp = blockSums, *ssrcp = ssrc;
        int Nv = N, Ev = E, nsv = nScan;
        void* cargs[] = {
            (void*)&eip, (void*)&wqp, (void*)&wkp, (void*)&wvp, (void*)&wop,
            (void*)&whip, (void*)&wlop, (void*)&histp, (void*)&offsp,
            (void*)&startsp, (void*)&bsp, (void*)&ssrcp,
            (void*)&Nv, (void*)&Ev, (void*)&nsv };
        hipError_t cerr = hipLaunchCooperativeKernel(
            (void*)preprocess_coop, dim3(1024), dim3(256), cargs, 0, stream);
        if (cerr != hipSuccess) {
            const int gzp = ((N > 65536 ? N : 65536) + 255) / 256;
            zero_prep<<<gzp, 256, 0, stream>>>(Wq, Wk, Wv, Wo, whi, wlo, hist, N);
            hist_kernel<<<(E + 255) / 256, 256, 0, stream>>>(ei, hist, E);
            scan_partial<<<nScan, SCAN_TPB, 0, stream>>>(hist, offs, blockSums, N);
            scan_add<<<(N + 255) / 256, 256, 0, stream>>>(offs, starts, blockSums, N, nScan);
            scatter_kernel<<<(E + 255) / 256, 256, 0, stream>>>(ei, offs, ssrc, E);
        }
    }

    const int gq = (N + BM - 1) / BM;
    qkv_mfma<<<gq, 256, 0, stream>>>(x, whi, wlo, Q16, KV16, N);

    node_agg<<<(N + 3) / 4, 256, 0, stream>>>(ssrc, starts, offs, Q16, KV16, agg, N);

    out_ln_mfma<<<gq, 256, 0, stream>>>(agg, whi, wlo, bo, x, gamma, beta,
                                        (float*)d_out, N);
}

// Round 9
// 271.147 us; speedup vs baseline: 2.8601x; 2.8601x over previous
//
#include <hip/hip_runtime.h>
#include <math.h>

// N nodes (50000), E edges (600000), D=128.
// Q = x@Wq.T; K = x@Wk.T; V = x@Wv.T  (node-level)
// per edge e=(s->d): c = sigmoid(dot(Q[d],K[s])/sqrt(128)); agg[d] += c*V[s]
// out = LN(x + agg@Wo.T + bo) * gamma + beta
//
// R2..R8: counting-sort + per-node agg; split-bf16 MFMA GEMMs; K/V bf16
//     interleaved; node_agg sublane layout + superbatch + 1-deep pipeline;
//     Q bf16 pre-scaled. qkv (LDS, BM=64) = 46 us, node_agg ~45 us.
//     BEST MEASURED TOTAL: 268.2 us (round 2).
// R9: qkv grid x3 mat-split REGRESSED (staging tripled: 61.7 us).
// R10: qkv no-LDS reg-A REGRESSED HARD (107.8): B-stream x4 at 3 waves/SIMD.
// R11/R13: qkv QBM=32 REGRESSED (56 us): per-block B-traffic constant ->
//     doubling grid doubled B-reads. BM=64 is the tile optimum.
// R14: cooperative preprocess REGRESSED CATASTROPHICALLY (548 us): grid.sync
//     ~90us each on MI355X. Kernel-boundary >> grid.sync here.
// R15: revert to best-known assembly: 5-kernel preprocess + BM=64 qkv +
//     superbatch node_agg + out_ln. Re-anchor at ~268 us.

#define BM 64      /* qkv + out_ln tile */
#define QSCALE -0.08838834764831845f   /* -1/sqrt(128), folded into Q */

typedef __attribute__((ext_vector_type(8))) short bfrag;   // 8 bf16 = 4 VGPRs
typedef __attribute__((ext_vector_type(4))) float f32x4;

__device__ __forceinline__ short f2bf(float f) {
    union { float f; unsigned u; } v; v.f = f;
    unsigned r = v.u + 0x7FFFu + ((v.u >> 16) & 1u);   // round-to-nearest-even
    return (short)(r >> 16);
}
__device__ __forceinline__ float bf2f(short h) {
    union { unsigned u; float f; } v;
    v.u = ((unsigned)(unsigned short)h) << 16;
    return v.f;
}
// dword holds (K at low ushort, V at high ushort)
__device__ __forceinline__ float klo(unsigned w) {
    union { unsigned u; float f; } v; v.u = w << 16; return v.f;
}
__device__ __forceinline__ float vhi(unsigned w) {
    union { unsigned u; float f; } v; v.u = w & 0xffff0000u; return v.f;
}

#define SWZ(x, pat) __int_as_float(__builtin_amdgcn_ds_swizzle(__float_as_int(x), pat))

// ---------- fused: zero hist (N ints) + weight split fp32->bf16 hi/lo ----
__global__ __launch_bounds__(256) void zero_prep(
    const float* __restrict__ Wq, const float* __restrict__ Wk,
    const float* __restrict__ Wv, const float* __restrict__ Wo,
    short* __restrict__ whi, short* __restrict__ wlo,
    int* __restrict__ hist, int N)
{
    int g = blockIdx.x * 256 + threadIdx.x;
    if (g < N) hist[g] = 0;
    if (g < 65536) {
        const float* Ws[4] = {Wq, Wk, Wv, Wo};
        float f = Ws[g >> 14][g & 16383];
        short h = f2bf(f);
        short l = f2bf(f - bf2f(h));
        whi[g] = h; wlo[g] = l;
    }
}

// ---------------- counting sort of edges by dst ----------------
__global__ __launch_bounds__(256) void hist_kernel(
    const int* __restrict__ ei, int* __restrict__ hist, int E)
{
    int e = blockIdx.x * blockDim.x + threadIdx.x;
    if (e < E) atomicAdd(&hist[ei[E + e]], 1);
}

#define SCAN_TPB 256
#define SCAN_EPT 4   // 1024 elements per scan block -> nb = ceil(N/1024) <= 64

__global__ __launch_bounds__(SCAN_TPB) void scan_partial(
    const int* __restrict__ hist, int* __restrict__ offs,
    int* __restrict__ blockSums, int N)
{
    __shared__ int sdata[SCAN_TPB];
    int b = blockIdx.x;
    int t = threadIdx.x;
    int base = b * SCAN_TPB * SCAN_EPT + t * SCAN_EPT;
    int v[SCAN_EPT];
    int tot = 0;
    #pragma unroll
    for (int j = 0; j < SCAN_EPT; ++j) {
        int idx = base + j;
        v[j] = (idx < N) ? hist[idx] : 0;
        tot += v[j];
    }
    sdata[t] = tot;
    __syncthreads();
    for (int off = 1; off < SCAN_TPB; off <<= 1) {
        int xv = (t >= off) ? sdata[t - off] : 0;
        __syncthreads();
        sdata[t] += xv;
        __syncthreads();
    }
    int run = sdata[t] - tot;
    #pragma unroll
    for (int j = 0; j < SCAN_EPT; ++j) {
        int idx = base + j;
        if (idx < N) offs[idx] = run;
        run += v[j];
    }
    if (t == SCAN_TPB - 1) blockSums[b] = sdata[t];
}

// adds block prefix; each block wave-scans the <=64 blockSums locally.
__global__ __launch_bounds__(256) void scan_add(
    int* __restrict__ offs, int* __restrict__ starts,
    const int* __restrict__ blockSums, int N, int nb)
{
    __shared__ int bs[64];
    int t = threadIdx.x;
    if (t < 64) {
        int v = (t < nb) ? blockSums[t] : 0;
        #pragma unroll
        for (int off = 1; off < 64; off <<= 1) {
            int u = __shfl_up(v, off);
            if (t >= off) v += u;
        }
        bs[t] = v;   // inclusive scan
    }
    __syncthreads();
    int idx = blockIdx.x * blockDim.x + threadIdx.x;
    if (idx < N) {
        int blk = idx >> 10;
        int pref = (blk == 0) ? 0 : bs[blk - 1];
        int vv = offs[idx] + pref;
        offs[idx] = vv;
        starts[idx] = vv;
    }
}

// scatter: offs[d] consumed (becomes END offset after all increments)
__global__ __launch_bounds__(256) void scatter_kernel(
    const int* __restrict__ ei, int* __restrict__ offs,
    int* __restrict__ ssrc, int E)
{
    int e = blockIdx.x * blockDim.x + threadIdx.x;
    if (e < E) {
        int d = ei[E + e];
        int pos = atomicAdd(&offs[d], 1);
        ssrc[pos] = ei[e];
    }
}

// ---------------- fused QKV projection via split-bf16 MFMA ----------------
// R8 structure, BM=64 (proven 46 us). Q written bf16 pre-scaled by
// -1/sqrt(128); K,V element-interleaved bf16:
// KV16[node*256 + 2*i] = K[node][i], KV16[node*256 + 2*i + 1] = V[node][i]
__global__ __launch_bounds__(256) void qkv_mfma(
    const float* __restrict__ x,
    const short* __restrict__ whi, const short* __restrict__ wlo,
    unsigned short* __restrict__ Q16, unsigned short* __restrict__ KV16, int N)
{
    __shared__ short xs_hi[64][136];   // +8 pad: row 272 B -> 2-way LDS (free)
    __shared__ short xs_lo[64][136];

    const int tid = threadIdx.x;
    const int row0 = blockIdx.x * BM;

    #pragma unroll
    for (int i = 0; i < 8; ++i) {      // 64 rows x 32 float4 = 2048 = 256*8
        int idx = tid + 256 * i;
        int r = idx >> 5;
        int c4 = idx & 31;
        int gr = row0 + r;
        float4 val = make_float4(0.f, 0.f, 0.f, 0.f);
        if (gr < N) val = ((const float4*)(x + (size_t)gr * 128))[c4];
        short4 h, l;
        h.x = f2bf(val.x); l.x = f2bf(val.x - bf2f(h.x));
        h.y = f2bf(val.y); l.y = f2bf(val.y - bf2f(h.y));
        h.z = f2bf(val.z); l.z = f2bf(val.z - bf2f(h.z));
        h.w = f2bf(val.w); l.w = f2bf(val.w - bf2f(h.w));
        *((short4*)&xs_hi[r][c4 * 4]) = h;
        *((short4*)&xs_lo[r][c4 * 4]) = l;
    }
    __syncthreads();

    const int wid  = tid >> 6;
    const int lane = tid & 63;
    const int n16  = lane & 15;
    const int quad = lane >> 4;

    #pragma unroll 1
    for (int mat = 0; mat < 3; ++mat) {
        const short* __restrict__ WH = whi + mat * 16384;
        const short* __restrict__ WL = wlo + mat * 16384;
        const f32x4 zero = {0.f, 0.f, 0.f, 0.f};
        f32x4 acc[4][2];
        #pragma unroll
        for (int t = 0; t < 4; ++t) { acc[t][0] = zero; acc[t][1] = zero; }

        #pragma unroll
        for (int kc = 0; kc < 4; ++kc) {
            int k0 = kc * 32 + quad * 8;
            bfrag ah[4], al[4], bh[2], bl[2];
            #pragma unroll
            for (int t = 0; t < 4; ++t) {
                ah[t] = *((const bfrag*)&xs_hi[t * 16 + n16][k0]);
                al[t] = *((const bfrag*)&xs_lo[t * 16 + n16][k0]);
            }
            #pragma unroll
            for (int c = 0; c < 2; ++c) {
                int wr = (wid * 2 + c) * 16 + n16;
                bh[c] = *((const bfrag*)(WH + wr * 128 + k0));
                bl[c] = *((const bfrag*)(WL + wr * 128 + k0));
            }
            #pragma unroll
            for (int t = 0; t < 4; ++t)
                #pragma unroll
                for (int c = 0; c < 2; ++c) {
                    acc[t][c] = __builtin_amdgcn_mfma_f32_16x16x32_bf16(ah[t], bh[c], acc[t][c], 0, 0, 0);
                    acc[t][c] = __builtin_amdgcn_mfma_f32_16x16x32_bf16(al[t], bh[c], acc[t][c], 0, 0, 0);
                    acc[t][c] = __builtin_amdgcn_mfma_f32_16x16x32_bf16(ah[t], bl[c], acc[t][c], 0, 0, 0);
                }
        }
        #pragma unroll
        for (int t = 0; t < 4; ++t)
            #pragma unroll
            for (int r = 0; r < 4; ++r) {
                int grow = row0 + t * 16 + quad * 4 + r;
                if (grow < N) {
                    int c0 = (wid * 2 + 0) * 16 + n16;
                    int c1 = (wid * 2 + 1) * 16 + n16;
                    if (mat == 0) {
                        Q16[(size_t)grow * 128 + c0] = (unsigned short)f2bf(acc[t][0][r] * QSCALE);
                        Q16[(size_t)grow * 128 + c1] = (unsigned short)f2bf(acc[t][1][r] * QSCALE);
                    } else {
                        size_t base = (size_t)grow * 256 + (mat - 1);  // K at +0, V at +1
                        KV16[base + 2 * c0] = (unsigned short)f2bf(acc[t][0][r]);
                        KV16[base + 2 * c1] = (unsigned short)f2bf(acc[t][1][r]);
                    }
                }
            }
    }
}

// ---------------- per-node attention aggregation (no atomics) ----------------
// One wave per dst node; 4 edge slots (lane>>4) x 16 sublanes (lane&15) x 8
// elements; one 4-step swizzle allreduce serves 4 edges. Superbatch index
// preload: lane l holds ssrc[base+l], per-batch indices via __shfl; KV
// prefetch for batch b+1 issued before computing batch b.
__global__ __launch_bounds__(256) void node_agg(
    const int* __restrict__ ssrc,
    const int* __restrict__ starts,
    const int* __restrict__ endoffs,
    const unsigned short* __restrict__ Q16,
    const unsigned short* __restrict__ KV16,
    float* __restrict__ agg, int N)
{
    int node = blockIdx.x * 4 + (threadIdx.x >> 6);
    if (node >= N) return;
    int lane = threadIdx.x & 63;
    int eg   = lane >> 4;        // edge slot 0..3
    int sl   = lane & 15;        // element group: elements sl*8 .. sl*8+7
    int start = starts[node];
    int end   = endoffs[node];

    if (start >= end) {          // degree-0 node: zero output, avoid ssrc[-1]
        if (eg == 0) {
            *((float4*)(agg + (size_t)node * 128 + sl * 8))     = make_float4(0.f, 0.f, 0.f, 0.f);
            *((float4*)(agg + (size_t)node * 128 + sl * 8 + 4)) = make_float4(0.f, 0.f, 0.f, 0.f);
        }
        return;
    }

    // q: one 16B bf16x8 load, unpacked once
    bfrag qv = *((const bfrag*)(Q16 + (size_t)node * 128 + sl * 8));
    float q0x = bf2f(qv[0]), q0y = bf2f(qv[1]), q0z = bf2f(qv[2]), q0w = bf2f(qv[3]);
    float q1x = bf2f(qv[4]), q1y = bf2f(qv[5]), q1z = bf2f(qv[6]), q1w = bf2f(qv[7]);

    float a0 = 0.f, a1 = 0.f, a2 = 0.f, a3 = 0.f;
    float a4 = 0.f, a5 = 0.f, a6 = 0.f, a7 = 0.f;

    const unsigned short* kvbase = KV16 + sl * 16;   // + s*256 per edge

    for (int base = start; base < end; base += 64) {   // superbatch (deg<=64: once)
        int li = base + lane;
        li = (li < end) ? li : (end - 1);
        int sidx = ssrc[li];                            // 64 indices in one load
        int nb   = end - base;
        if (nb > 64) nb = 64;
        int nbat = (nb + 7) >> 3;                       // 1..8 batches of 8 edges

        // batch 0 loads
        int s0 = __shfl(sidx, eg);
        int s1 = __shfl(sidx, 4 + eg);
        const unsigned short* kp0 = kvbase + ((size_t)s0 << 8);
        const unsigned short* kp1 = kvbase + ((size_t)s1 << 8);
        uint4 wa0 = *((const uint4*)kp0);
        uint4 wa1 = *((const uint4*)(kp0 + 8));
        uint4 wb0 = *((const uint4*)kp1);
        uint4 wb1 = *((const uint4*)(kp1 + 8));

        for (int b = 0;;) {
            bool more = (b + 1) < nbat;                 // wave-uniform
            uint4 na0, na1, nb0, nb1;
            if (more) {                                  // prefetch batch b+1
                int t0 = __shfl(sidx, 8 * (b + 1) + eg);
                int t1 = __shfl(sidx, 8 * (b + 1) + 4 + eg);
                const unsigned short* np0 = kvbase + ((size_t)t0 << 8);
                const unsigned short* np1 = kvbase + ((size_t)t1 << 8);
                na0 = *((const uint4*)np0);
                na1 = *((const uint4*)(np0 + 8));
                nb0 = *((const uint4*)np1);
                nb1 = *((const uint4*)(np1 + 8));
            }

            int ok0 = ((base + 8 * b + eg) < end);
            int ok1 = ((base + 8 * b + 4 + eg) < end);

            // dot products (K in low ushort of each dword)
            float p0, p1;
            p0 = q0x * klo(wa0.x);
            p0 = fmaf(q0y, klo(wa0.y), p0);
            p0 = fmaf(q0z, klo(wa0.z), p0);
            p0 = fmaf(q0w, klo(wa0.w), p0);
            p0 = fmaf(q1x, klo(wa1.x), p0);
            p0 = fmaf(q1y, klo(wa1.y), p0);
            p0 = fmaf(q1z, klo(wa1.z), p0);
            p0 = fmaf(q1w, klo(wa1.w), p0);
            p1 = q0x * klo(wb0.x);
            p1 = fmaf(q0y, klo(wb0.y), p1);
            p1 = fmaf(q0z, klo(wb0.z), p1);
            p1 = fmaf(q0w, klo(wb0.w), p1);
            p1 = fmaf(q1x, klo(wb1.x), p1);
            p1 = fmaf(q1y, klo(wb1.y), p1);
            p1 = fmaf(q1z, klo(wb1.z), p1);
            p1 = fmaf(q1w, klo(wb1.w), p1);

            // 4-step allreduce within each 16-lane group (4 edges at once)
            p0 += SWZ(p0, 0x041F); p1 += SWZ(p1, 0x041F);
            p0 += SWZ(p0, 0x081F); p1 += SWZ(p1, 0x081F);
            p0 += SWZ(p0, 0x101F); p1 += SWZ(p1, 0x101F);
            p0 += SWZ(p0, 0x201F); p1 += SWZ(p1, 0x201F);

            // sigmoid(q.k/sqrt(D)): Q pre-scaled negative -> c = 1/(1+exp(p))
            float c0 = __builtin_amdgcn_rcpf(1.f + __expf(p0));
            float c1 = __builtin_amdgcn_rcpf(1.f + __expf(p1));
            if (!ok0) c0 = 0.f;
            if (!ok1) c1 = 0.f;

            // accumulate c*V (V in high ushort of each dword)
            a0 = fmaf(c0, vhi(wa0.x), a0); a0 = fmaf(c1, vhi(wb0.x), a0);
            a1 = fmaf(c0, vhi(wa0.y), a1); a1 = fmaf(c1, vhi(wb0.y), a1);
            a2 = fmaf(c0, vhi(wa0.z), a2); a2 = fmaf(c1, vhi(wb0.z), a2);
            a3 = fmaf(c0, vhi(wa0.w), a3); a3 = fmaf(c1, vhi(wb0.w), a3);
            a4 = fmaf(c0, vhi(wa1.x), a4); a4 = fmaf(c1, vhi(wb1.x), a4);
            a5 = fmaf(c0, vhi(wa1.y), a5); a5 = fmaf(c1, vhi(wb1.y), a5);
            a6 = fmaf(c0, vhi(wa1.z), a6); a6 = fmaf(c1, vhi(wb1.z), a6);
            a7 = fmaf(c0, vhi(wa1.w), a7); a7 = fmaf(c1, vhi(wb1.w), a7);

            if (!more) break;
            wa0 = na0; wa1 = na1; wb0 = nb0; wb1 = nb1;
            ++b;
        }
    }

    // combine the 4 edge-slot groups: xor16 (swizzle) + xor32 (shfl)
    a0 += SWZ(a0, 0x401F); a1 += SWZ(a1, 0x401F);
    a2 += SWZ(a2, 0x401F); a3 += SWZ(a3, 0x401F);
    a4 += SWZ(a4, 0x401F); a5 += SWZ(a5, 0x401F);
    a6 += SWZ(a6, 0x401F); a7 += SWZ(a7, 0x401F);
    a0 += __shfl_xor(a0, 32); a1 += __shfl_xor(a1, 32);
    a2 += __shfl_xor(a2, 32); a3 += __shfl_xor(a3, 32);
    a4 += __shfl_xor(a4, 32); a5 += __shfl_xor(a5, 32);
    a6 += __shfl_xor(a6, 32); a7 += __shfl_xor(a7, 32);

    if (eg == 0) {
        *((float4*)(agg + (size_t)node * 128 + sl * 8))     = make_float4(a0, a1, a2, a3);
        *((float4*)(agg + (size_t)node * 128 + sl * 8 + 4)) = make_float4(a4, a5, a6, a7);
    }
}

// ------- output GEMM (split-bf16 MFMA) + bias + residual + LayerNorm -------
__global__ __launch_bounds__(256) void out_ln_mfma(
    const float* __restrict__ agg,
    const short* __restrict__ whi, const short* __restrict__ wlo,  // Wo = mat 3
    const float* __restrict__ bo, const float* __restrict__ x,
    const float* __restrict__ gamma, const float* __restrict__ beta,
    float* __restrict__ out, int N)
{
    __shared__ __align__(16) char smem[64 * 136 * 2 * 2];   // 69632 B
    short (*xs_hi)[136] = (short(*)[136])smem;
    short (*xs_lo)[136] = (short(*)[136])(smem + 64 * 136 * 2);
    float (*hs)[132]    = (float(*)[132])smem;               // reused post-GEMM

    const int tid = threadIdx.x;
    const int row0 = blockIdx.x * BM;

    #pragma unroll
    for (int i = 0; i < 8; ++i) {
        int idx = tid + 256 * i;
        int r = idx >> 5;
        int c4 = idx & 31;
        int gr = row0 + r;
        float4 val = make_float4(0.f, 0.f, 0.f, 0.f);
        if (gr < N) val = ((const float4*)(agg + (size_t)gr * 128))[c4];
        short4 h, l;
        h.x = f2bf(val.x); l.x = f2bf(val.x - bf2f(h.x));
        h.y = f2bf(val.y); l.y = f2bf(val.y - bf2f(h.y));
        h.z = f2bf(val.z); l.z = f2bf(val.z - bf2f(h.z));
        h.w = f2bf(val.w); l.w = f2bf(val.w - bf2f(h.w));
        *((short4*)&xs_hi[r][c4 * 4]) = h;
        *((short4*)&xs_lo[r][c4 * 4]) = l;
    }
    __syncthreads();

    const int wid  = tid >> 6;
    const int lane = tid & 63;
    const int n16  = lane & 15;
    const int quad = lane >> 4;
    const short* __restrict__ WH = whi + 3 * 16384;
    const short* __restrict__ WL = wlo + 3 * 16384;

    const f32x4 zero = {0.f, 0.f, 0.f, 0.f};
    f32x4 acc[4][2];
    #pragma unroll
    for (int t = 0; t < 4; ++t) { acc[t][0] = zero; acc[t][1] = zero; }

    #pragma unroll
    for (int kc = 0; kc < 4; ++kc) {
        int k0 = kc * 32 + quad * 8;
        bfrag ah[4], al[4], bh[2], bl[2];
        #pragma unroll
        for (int t = 0; t < 4; ++t) {
            ah[t] = *((const bfrag*)&xs_hi[t * 16 + n16][k0]);
            al[t] = *((const bfrag*)&xs_lo[t * 16 + n16][k0]);
        }
        #pragma unroll
        for (int c = 0; c < 2; ++c) {
            int wr = (wid * 2 + c) * 16 + n16;
            bh[c] = *((const bfrag*)(WH + wr * 128 + k0));
            bl[c] = *((const bfrag*)(WL + wr * 128 + k0));
        }
        #pragma unroll
        for (int t = 0; t < 4; ++t)
            #pragma unroll
            for (int c = 0; c < 2; ++c) {
                acc[t][c] = __builtin_amdgcn_mfma_f32_16x16x32_bf16(ah[t], bh[c], acc[t][c], 0, 0, 0);
                acc[t][c] = __builtin_amdgcn_mfma_f32_16x16x32_bf16(al[t], bh[c], acc[t][c], 0, 0, 0);
                acc[t][c] = __builtin_amdgcn_mfma_f32_16x16x32_bf16(ah[t], bl[c], acc[t][c], 0, 0, 0);
            }
    }
    __syncthreads();   // all xs reads done before hs overwrite

    #pragma unroll
    for (int t = 0; t < 4; ++t)
        #pragma unroll
        for (int r = 0; r < 4; ++r) {
            hs[t * 16 + quad * 4 + r][(wid * 2 + 0) * 16 + n16] = acc[t][0][r];
            hs[t * 16 + quad * 4 + r][(wid * 2 + 1) * 16 + n16] = acc[t][1][r];
        }
    __syncthreads();

    {
        int r = tid >> 2;
        int qd = tid & 3;
        int gr = row0 + r;
        float sum = 0.f, sq = 0.f;
        #pragma unroll
        for (int c = 0; c < 32; c += 4) {
            float4 g4 = *((float4*)&hs[r][qd * 32 + c]);
            float4 b4 = *((const float4*)(bo + qd * 32 + c));
            float4 x4 = make_float4(0.f, 0.f, 0.f, 0.f);
            if (gr < N) x4 = *((const float4*)(x + (size_t)gr * 128 + qd * 32 + c));
            float4 h = make_float4(g4.x + b4.x + x4.x, g4.y + b4.y + x4.y,
                                   g4.z + b4.z + x4.z, g4.w + b4.w + x4.w);
            *((float4*)&hs[r][qd * 32 + c]) = h;
            sum += h.x + h.y + h.z + h.w;
            sq += h.x * h.x + h.y * h.y + h.z * h.z + h.w * h.w;
        }
        sum += __shfl_xor(sum, 1); sum += __shfl_xor(sum, 2);
        sq  += __shfl_xor(sq, 1);  sq  += __shfl_xor(sq, 2);
        float mu = sum * (1.f / 128.f);
        float var = sq * (1.f / 128.f) - mu * mu;
        float rs = rsqrtf(var + 1e-5f);
        if (gr < N) {
            #pragma unroll
            for (int c = 0; c < 32; c += 4) {
                float4 h = *((float4*)&hs[r][qd * 32 + c]);
                float4 g = *((const float4*)(gamma + qd * 32 + c));
                float4 b = *((const float4*)(beta + qd * 32 + c));
                float4 o = make_float4((h.x - mu) * rs * g.x + b.x,
                                       (h.y - mu) * rs * g.y + b.y,
                                       (h.z - mu) * rs * g.z + b.z,
                                       (h.w - mu) * rs * g.w + b.w);
                *((float4*)(out + (size_t)gr * 128 + qd * 32 + c)) = o;
            }
        }
    }
}

extern "C" void kernel_launch(void* const* d_in, const int* in_sizes, int n_in,
                              void* d_out, int out_size, void* d_ws, size_t ws_size,
                              hipStream_t stream) {
    const float* x     = (const float*)d_in[0];
    const int*   ei    = (const int*)d_in[1];
    const float* Wq    = (const float*)d_in[2];
    const float* Wk    = (const float*)d_in[3];
    const float* Wv    = (const float*)d_in[4];
    const float* Wo    = (const float*)d_in[5];
    const float* bo    = (const float*)d_in[6];
    const float* gamma = (const float*)d_in[7];
    const float* beta  = (const float*)d_in[8];
    const int N = in_sizes[0] / 128;
    const int E = in_sizes[1] / 2;
    const size_t ND = (size_t)N * 128;

    // workspace: Q16 bf16 12.8MB + KV16 interleaved bf16 25.6MB + agg 25.6MB
    //            + hist/offs/starts + blockSums + ssrc + whi/wlo
    unsigned short* Q16  = (unsigned short*)d_ws;
    unsigned short* KV16 = Q16 + ND;                     // 2*ND ushorts
    float* agg = (float*)(KV16 + 2 * ND);
    int* hist      = (int*)(agg + ND);
    int* offs      = hist + N;
    int* starts    = offs + N;
    int* blockSums = starts + N;       // 256 ints
    int* ssrc      = blockSums + 256;  // E ints
    short* whi     = (short*)(ssrc + E);        // 4*16384 shorts
    short* wlo     = whi + 4 * 16384;

    const int gzp = ((N > 65536 ? N : 65536) + 255) / 256;
    zero_prep<<<gzp, 256, 0, stream>>>(Wq, Wk, Wv, Wo, whi, wlo, hist, N);

    hist_kernel<<<(E + 255) / 256, 256, 0, stream>>>(ei, hist, E);
    const int nScan = (N + SCAN_TPB * SCAN_EPT - 1) / (SCAN_TPB * SCAN_EPT);
    scan_partial<<<nScan, SCAN_TPB, 0, stream>>>(hist, offs, blockSums, N);
    scan_add<<<(N + 255) / 256, 256, 0, stream>>>(offs, starts, blockSums, N, nScan);
    scatter_kernel<<<(E + 255) / 256, 256, 0, stream>>>(ei, offs, ssrc, E);

    const int gq = (N + BM - 1) / BM;
    qkv_mfma<<<gq, 256, 0, stream>>>(x, whi, wlo, Q16, KV16, N);

    node_agg<<<(N + 3) / 4, 256, 0, stream>>>(ssrc, starts, offs, Q16, KV16, agg, N);

    out_ln_mfma<<<gq, 256, 0, stream>>>(agg, whi, wlo, bo, x, gamma, beta,
                                        (float*)d_out, N);
}